// Round 1
// baseline (359.867 us; speedup 1.0000x reference)
//
#include <hip/hip_runtime.h>
#include <hip/hip_bf16.h>

// Problem constants (match reference file)
constexpr int K    = 8192;
constexpr int N4   = 6144;    // int4 rows
constexpr int N8   = 2048;    // uint8 rows
constexpr int NT   = N4 + N8; // 8192 output columns
constexpr int NG   = K / 128; // 64 groups per int4 row

typedef short  short8  __attribute__((ext_vector_type(8)));
typedef float  floatx4 __attribute__((ext_vector_type(4)));

__device__ inline short f2bf(float f) {
    __hip_bfloat16 h = __float2bfloat16(f);   // RNE
    return __builtin_bit_cast(short, h);
}

// ---------------------------------------------------------------------------
// Prep: x2bf = bf16(x/awq) stored in MFMA A-fragment order:
//   x2bf[c*512 + lane*8 + j] = X[m = lane&15][k = c*32 + (lane>>4)*8 + j]
// Also: fwd = inverse of inv_perm.
// ---------------------------------------------------------------------------
__global__ void prep_kernel(const float* __restrict__ x,
                            const float* __restrict__ awq,
                            const int*   __restrict__ inv_perm,
                            short* __restrict__ x2bf,
                            int*   __restrict__ fwd) {
    const int tid  = blockIdx.x * blockDim.x + threadIdx.x;   // 0..131071
    const int c    = tid >> 9;
    const int rem  = tid & 511;
    const int lane = rem >> 3;
    const int j    = rem & 7;
    const int m    = lane & 15;
    const int k    = c * 32 + (lane >> 4) * 8 + j;
    x2bf[tid] = f2bf(x[m * K + k] / awq[k]);
    if (tid < NT) fwd[inv_perm[tid]] = tid;
}

// ---------------------------------------------------------------------------
// Single-pass MFMA GEMV, no atomics, no split-K partials.
// Block = 8 waves (512 threads) = one 16-row tile; wave w covers
// k in [w*1024, w*1024+1024) as 32 chunks of 32 k.
// 4096 waves total -> 4 waves/SIMD (vs 2 before): double the TLP to hide
// HBM latency during the per-group vmcnt waits.
// Pipeline stage = 2 chunks (64 k): 2-stage A/B buffers (~48 buffer VGPRs,
// est. ~85 total -> no spill under the __launch_bounds__(512,4) 128-VGPR cap).
// Tail is peeled: no dummy reload (saves ~24 MB of wasted HBM traffic).
//   int4 rows : wf = w*s - 8s      (group scale s, one scale per 4 chunks)
//   uint8 rows: wf = w - 128       (exact in bf16; s8 applied in epilogue;
//               algebraic merge of hi/lo nibbles + 8*s*sum_x correction)
// Epilogue: 8KB LDS cross-wave reduce, then 256 threads apply s8/perm/bias
// and write each output element exactly once.
// ---------------------------------------------------------------------------
__global__ __launch_bounds__(512, 4)
void qgemv_kernel(const short* __restrict__ xf,
                  const int*   __restrict__ w4,
                  const float* __restrict__ s4,
                  const int*   __restrict__ w8,
                  const float* __restrict__ s8,
                  const int*   __restrict__ fwd,
                  const float* __restrict__ bias,
                  float* __restrict__ out) {
    __shared__ float lds[8 * 256];

    const int t    = threadIdx.x;
    const int lane = t & 63;
    const int w    = t >> 6;            // wave 0..7
    const int nb   = blockIdx.x * 16;   // tile base row
    const int i    = lane & 15;
    const int q    = lane >> 4;
    const int row  = nb + i;            // this lane's weight row

    const bool is4 = (nb < N4);
    const int*   wp = (is4 ? (w4 + (size_t)row * K)
                           : (w8 + (size_t)(row - N4) * K))
                      + (size_t)w * 1024 + q * 8;          // + chunk*32 later
    const short* xw = xf + (size_t)w * 32 * 512 + lane * 8; // + chunk*512 later
    const float* sp = is4 ? (s4 + (size_t)row * NG + w * 8) : nullptr; // + g>>1

    floatx4 acc = {0.f, 0.f, 0.f, 0.f};

    int4   wbA[4], wbB[4];
    short8 abA[2], abB[2];
    float  sA = 0.f, sB = 0.f;

    // group = 2 chunks = 64 k. 16 groups per wave.
    auto loadg = [&](int g, int4* wb, short8* ab, float& s) {
        #pragma unroll
        for (int c = 0; c < 2; ++c) {
            const size_t co = (size_t)(g * 2 + c);
            wb[2 * c]     = *(const int4*)(wp + co * 32);
            wb[2 * c + 1] = *(const int4*)(wp + co * 32 + 4);
            ab[c]         = *(const short8*)(xw + co * 512);
        }
        if (is4) s = sp[g >> 1];   // scale group = 128 k = 4 chunks = 2 groups
    };

    auto compg = [&](const int4* wb, const short8* ab, float s) {
        const float sc = is4 ? s : 1.f;
        const float sb = is4 ? -8.f * s : -128.f;
        #pragma unroll
        for (int c = 0; c < 2; ++c) {
            const int4 wa = wb[2 * c];
            const int4 wz = wb[2 * c + 1];
            short8 bf;
            bf[0] = f2bf((float)wa.x * sc + sb);
            bf[1] = f2bf((float)wa.y * sc + sb);
            bf[2] = f2bf((float)wa.z * sc + sb);
            bf[3] = f2bf((float)wa.w * sc + sb);
            bf[4] = f2bf((float)wz.x * sc + sb);
            bf[5] = f2bf((float)wz.y * sc + sb);
            bf[6] = f2bf((float)wz.z * sc + sb);
            bf[7] = f2bf((float)wz.w * sc + sb);
            acc = __builtin_amdgcn_mfma_f32_16x16x32_bf16(ab[c], bf, acc, 0, 0, 0);
        }
    };

    // 16 groups, 2-stage manual pipeline (A/B buffers), peeled tail.
    loadg(0, wbA, abA, sA);
    #pragma unroll 1
    for (int g = 0; g < 14; g += 2) {
        loadg(g + 1, wbB, abB, sB);
        compg(wbA, abA, sA);          // group g
        loadg(g + 2, wbA, abA, sA);
        compg(wbB, abB, sB);          // group g+1
    }
    loadg(15, wbB, abB, sB);
    compg(wbA, abA, sA);              // group 14
    compg(wbB, abB, sB);              // group 15

    // ---- cross-wave reduce + fused scale/perm/bias writeout ----
    #pragma unroll
    for (int r = 0; r < 4; ++r)
        lds[w * 256 + (q * 4 + r) * 16 + i] = acc[r];
    __syncthreads();

    if (t < 256) {
        const int m  = t >> 4;     // 0..15 (batch row)
        const int i2 = t & 15;     // 0..15 (tile col)
        float v = 0.f;
        #pragma unroll
        for (int w2 = 0; w2 < 8; ++w2) v += lds[w2 * 256 + t];
        const int n  = nb + i2;
        const float sc = is4 ? 1.f : s8[n - N4];
        const int d  = fwd[n];
        out[(size_t)m * NT + d] = v * sc + bias[d];
    }
}

// ---------------------------------------------------------------------------
extern "C" void kernel_launch(void* const* d_in, const int* in_sizes, int n_in,
                              void* d_out, int out_size, void* d_ws, size_t ws_size,
                              hipStream_t stream) {
    const float* x        = (const float*)d_in[0];
    const int*   w_int4   = (const int*)  d_in[1];
    const float* s_int4   = (const float*)d_in[2];
    const int*   w_uint8  = (const int*)  d_in[3];
    const float* s_int8   = (const float*)d_in[4];
    const float* awq      = (const float*)d_in[5];
    const float* bias     = (const float*)d_in[6];
    const int*   inv_perm = (const int*)  d_in[7];
    // d_in[8] = group_size (==128), compile-time constant here

    short* x2bf = (short*)d_ws;                                       // 256 KB
    int*   fwd  = (int*)((char*)d_ws + (size_t)16 * K * sizeof(short)); // 32 KB

    prep_kernel<<<(16 * K) / 256, 256, 0, stream>>>(x, awq, inv_perm, x2bf, fwd);
    qgemv_kernel<<<NT / 16, 512, 0, stream>>>(x2bf, w_int4, s_int4,
                                              w_uint8, s_int8, fwd, bias,
                                              (float*)d_out);
}

// Round 3
// 336.701 us; speedup vs baseline: 1.0688x; 1.0688x over previous
//
#include <hip/hip_runtime.h>
#include <hip/hip_bf16.h>

// Problem constants (match reference file)
constexpr int K    = 8192;
constexpr int N4   = 6144;    // int4 rows
constexpr int N8   = 2048;    // uint8 rows
constexpr int NT   = N4 + N8; // 8192 output columns
constexpr int NG   = K / 128; // 64 groups per int4 row
constexpr int KS   = 4096;    // K per split (split-K x2)

typedef short  short8  __attribute__((ext_vector_type(8)));
typedef float  floatx4 __attribute__((ext_vector_type(4)));

__device__ inline short f2bf(float f) {
    __hip_bfloat16 h = __float2bfloat16(f);   // RNE
    return __builtin_bit_cast(short, h);
}

// ---------------------------------------------------------------------------
// Prep: x2bf = bf16(x/awq) stored in MFMA A-fragment order:
//   x2bf[c*512 + lane*8 + j] = X[m = lane&15][k = c*32 + (lane>>4)*8 + j]
// Also: fwd = inverse of inv_perm, and out pre-filled with bias (the GEMV
// kernel accumulates into out with atomics; bias folds in for free here
// since prep's 131072 threads map 1:1 onto out's 16x8192 elements).
// ---------------------------------------------------------------------------
__global__ void prep_kernel(const float* __restrict__ x,
                            const float* __restrict__ awq,
                            const int*   __restrict__ inv_perm,
                            const float* __restrict__ bias,
                            short* __restrict__ x2bf,
                            int*   __restrict__ fwd,
                            float* __restrict__ out) {
    const int tid  = blockIdx.x * blockDim.x + threadIdx.x;   // 0..131071
    const int c    = tid >> 9;
    const int rem  = tid & 511;
    const int lane = rem >> 3;
    const int j    = rem & 7;
    const int m    = lane & 15;
    const int k    = c * 32 + (lane >> 4) * 8 + j;
    x2bf[tid] = f2bf(x[m * K + k] / awq[k]);
    if (tid < NT) fwd[inv_perm[tid]] = tid;
    out[tid] = bias[tid & (NT - 1)];          // out = bias, pre-perm indexed
}

// ---------------------------------------------------------------------------
// Split-K x2 MFMA GEMV. Block = 4 waves (256 thr) = one 16-row tile x one
// half of K; wave w covers k in [split*4096 + w*1024, +1024) as 32 chunks
// of 32 k. 1024 blocks -> 4096 waves -> 4 waves/SIMD, exactly 4 blocks/CU.
// Per-wave inner loop is the round-0 proven shape: 8 groups of 4 chunks,
// 2-stage A/B register pipeline (12 16B loads in flight per stage).
// sched_barrier(0) after each load-group pins the loads above the compute
// phase so the scheduler cannot sink them and collapse the double buffer
// (round-1 failure mode: VGPR squeezed to 40, pipeline serialized).
//   int4 rows : wf = w*s - 8s      (group scale s, one per 4 chunks)
//   uint8 rows: wf = w - 128       (exact in bf16; s8 applied in epilogue;
//               algebraic merge of hi/lo nibbles + 8*s*sum_x correction)
// Epilogue: 4KB LDS cross-wave reduce, then 256 threads apply s8/perm and
// atomicAdd into out (bias already there; 2 atomic updates per element).
// ---------------------------------------------------------------------------
__global__ __launch_bounds__(256, 4)
void qgemv_kernel(const short* __restrict__ xf,
                  const int*   __restrict__ w4,
                  const float* __restrict__ s4,
                  const int*   __restrict__ w8,
                  const float* __restrict__ s8,
                  const int*   __restrict__ fwd,
                  float* __restrict__ out) {
    __shared__ float lds[4 * 256];

    const int t     = threadIdx.x;
    const int lane  = t & 63;
    const int w     = t >> 6;              // wave 0..3
    const int tile  = blockIdx.x >> 1;
    const int split = blockIdx.x & 1;
    const int nb    = tile * 16;           // tile base row
    const int i     = lane & 15;
    const int q     = lane >> 4;
    const int row   = nb + i;              // this lane's weight row

    const bool is4  = (nb < N4);
    const int kbase = split * KS + w * 1024;
    const int*   wp = (is4 ? (w4 + (size_t)row * K)
                           : (w8 + (size_t)(row - N4) * K))
                      + kbase + q * 8;                       // + chunk*32 later
    const short* xw = xf + (size_t)(kbase >> 5) * 512 + lane * 8; // + chunk*512
    const float* sp = is4 ? (s4 + (size_t)row * NG + (kbase >> 7)) : nullptr;

    floatx4 acc = {0.f, 0.f, 0.f, 0.f};

    int4   wbA[8], wbB[8];
    short8 abA[4], abB[4];
    float  sA = 0.f, sB = 0.f;

    // group = 4 chunks = 128 k (one scale group). 8 groups per wave.
    auto loadg = [&](int g, int4* wb, short8* ab, float& s) {
        #pragma unroll
        for (int c = 0; c < 4; ++c) {
            const size_t co = (size_t)(g * 4 + c);
            wb[2 * c]     = *(const int4*)(wp + co * 32);
            wb[2 * c + 1] = *(const int4*)(wp + co * 32 + 4);
            ab[c]         = *(const short8*)(xw + co * 512);
        }
        if (is4) s = sp[g];
    };

    auto compg = [&](const int4* wb, const short8* ab, float s) {
        const float sc = is4 ? s : 1.f;
        const float sb = is4 ? -8.f * s : -128.f;
        #pragma unroll
        for (int c = 0; c < 4; ++c) {
            const int4 wa = wb[2 * c];
            const int4 wz = wb[2 * c + 1];
            short8 bf;
            bf[0] = f2bf((float)wa.x * sc + sb);
            bf[1] = f2bf((float)wa.y * sc + sb);
            bf[2] = f2bf((float)wa.z * sc + sb);
            bf[3] = f2bf((float)wa.w * sc + sb);
            bf[4] = f2bf((float)wz.x * sc + sb);
            bf[5] = f2bf((float)wz.y * sc + sb);
            bf[6] = f2bf((float)wz.z * sc + sb);
            bf[7] = f2bf((float)wz.w * sc + sb);
            acc = __builtin_amdgcn_mfma_f32_16x16x32_bf16(ab[c], bf, acc, 0, 0, 0);
        }
    };

    // 8 groups, 2-stage manual pipeline (A/B buffers), peeled tail.
    loadg(0, wbA, abA, sA);
    __builtin_amdgcn_sched_barrier(0);
    #pragma unroll 1
    for (int g = 0; g < 6; g += 2) {
        loadg(g + 1, wbB, abB, sB);
        __builtin_amdgcn_sched_barrier(0);
        compg(wbA, abA, sA);              // group g
        loadg(g + 2, wbA, abA, sA);
        __builtin_amdgcn_sched_barrier(0);
        compg(wbB, abB, sB);              // group g+1
    }
    loadg(7, wbB, abB, sB);
    __builtin_amdgcn_sched_barrier(0);
    compg(wbA, abA, sA);                  // group 6
    compg(wbB, abB, sB);                  // group 7

    // ---- cross-wave reduce + fused scale/perm atomic writeout ----
    #pragma unroll
    for (int r = 0; r < 4; ++r)
        lds[w * 256 + (q * 4 + r) * 16 + i] = acc[r];
    __syncthreads();

    {
        const int m  = t >> 4;     // 0..15 (batch row)
        const int i2 = t & 15;     // 0..15 (tile col)
        const float v = lds[0 * 256 + t] + lds[1 * 256 + t]
                      + lds[2 * 256 + t] + lds[3 * 256 + t];
        const int n  = nb + i2;
        const float sc = is4 ? 1.f : s8[n - N4];
        const int d  = fwd[n];
        atomicAdd(&out[(size_t)m * NT + d], v * sc);
    }
}

// ---------------------------------------------------------------------------
extern "C" void kernel_launch(void* const* d_in, const int* in_sizes, int n_in,
                              void* d_out, int out_size, void* d_ws, size_t ws_size,
                              hipStream_t stream) {
    const float* x        = (const float*)d_in[0];
    const int*   w_int4   = (const int*)  d_in[1];
    const float* s_int4   = (const float*)d_in[2];
    const int*   w_uint8  = (const int*)  d_in[3];
    const float* s_int8   = (const float*)d_in[4];
    const float* awq      = (const float*)d_in[5];
    const float* bias     = (const float*)d_in[6];
    const int*   inv_perm = (const int*)  d_in[7];
    // d_in[8] = group_size (==128), compile-time constant here

    short* x2bf = (short*)d_ws;                                       // 256 KB
    int*   fwd  = (int*)((char*)d_ws + (size_t)16 * K * sizeof(short)); // 32 KB

    prep_kernel<<<(16 * K) / 256, 256, 0, stream>>>(x, awq, inv_perm, bias,
                                                    x2bf, fwd, (float*)d_out);
    qgemv_kernel<<<(NT / 16) * 2, 256, 0, stream>>>(x2bf, w_int4, s_int4,
                                                    w_uint8, s_int8, fwd,
                                                    (float*)d_out);
}